// Round 2
// baseline (193.689 us; speedup 1.0000x reference)
//
#include <hip/hip_runtime.h>

static constexpr int C    = 64;
static constexpr int H    = 128;
static constexpr int W    = 128;
static constexpr int NPIX = H * W;      // 16384
static constexpr int PAD  = 3;          // WS=7 -> +-3

// ---------------------------------------------------------------------------
// 1) conv1x1: out[o, p] = sum_c W[o,c] * x[c, p] + b[o]   (z selects q/k/v)
//    grid (NPIX/256, 3), block 256
// ---------------------------------------------------------------------------
__global__ __launch_bounds__(256) void k_conv(
    const float* __restrict__ x,
    const float* __restrict__ Wq, const float* __restrict__ bq,
    const float* __restrict__ Wk, const float* __restrict__ bk,
    const float* __restrict__ Wv, const float* __restrict__ bv,
    float* __restrict__ qo, float* __restrict__ ko, float* __restrict__ vo)
{
    __shared__ float Wl[C * C];           // 16 KB
    const int tid  = threadIdx.x;
    const int base = blockIdx.x * 256;
    const int z    = blockIdx.y;
    const float* Wm = (z == 0) ? Wq : (z == 1) ? Wk : Wv;
    const float* bm = (z == 0) ? bq : (z == 1) ? bk : bv;
    float* outm     = (z == 0) ? qo : (z == 1) ? ko : vo;

    for (int i = tid; i < C * C; i += 256) Wl[i] = Wm[i];

    float xr[C];
#pragma unroll
    for (int c = 0; c < C; ++c) xr[c] = x[c * NPIX + base + tid];
    __syncthreads();

#pragma unroll 4
    for (int o = 0; o < C; ++o) {
        float acc = bm[o];
#pragma unroll
        for (int c = 0; c < C; ++c) acc += Wl[o * C + c] * xr[c];
        outm[o * NPIX + base + tid] = acc;
    }
}

// ---------------------------------------------------------------------------
// 2) row Gram: S[h, w, kk] = sum_c q[c,h,w] * k[c,h,kk]
//    grid (H, 2 w-halves), block 256
// ---------------------------------------------------------------------------
__global__ __launch_bounds__(256) void k_gram(
    const float* __restrict__ q, const float* __restrict__ kmat,
    float* __restrict__ S)
{
    __shared__ float qs[C][64];   // this block's w-half of q row   (16 KB)
    __shared__ float ks[C][W];    // full k row                     (32 KB)
    const int h    = blockIdx.x;
    const int half = blockIdx.y;
    const int tid  = threadIdx.x;

    for (int i = tid; i < C * W; i += 256) {
        int c = i >> 7, kk = i & 127;
        ks[c][kk] = kmat[c * NPIX + h * W + kk];
    }
    for (int i = tid; i < C * 64; i += 256) {
        int c = i >> 6, wl = i & 63;
        qs[c][wl] = q[c * NPIX + h * W + half * 64 + wl];
    }
    __syncthreads();

    const int kk = tid & 127;
    float ksr[C];
#pragma unroll
    for (int c = 0; c < C; ++c) ksr[c] = ks[c][kk];

    const int wl0 = (tid >> 7);                 // 0 or 1
    for (int j = 0; j < 32; ++j) {
        int wl = wl0 + 2 * j;                   // local w in [0,64)
        float acc = 0.f;
#pragma unroll
        for (int c = 0; c < C; ++c) acc += qs[c][wl] * ksr[c];
        int w = half * 64 + wl;
        S[(h * W + w) * W + kk] = acc;
    }
}

// ---------------------------------------------------------------------------
// 3) diagonal 7-sum: T[h,w,kk] = sum_{d=-3..3} S[h, w+d, kk+d] (in-bounds only)
// ---------------------------------------------------------------------------
__global__ __launch_bounds__(256) void k_diag(
    const float* __restrict__ S, float* __restrict__ T)
{
    const int idx = blockIdx.x * 256 + threadIdx.x;   // < H*W*W
    const int kk = idx & 127;
    const int w  = (idx >> 7) & 127;
    float acc = 0.f;
#pragma unroll
    for (int d = -PAD; d <= PAD; ++d) {
        int wj = w + d, kj = kk + d;
        if (wj >= 0 && wj < W && kj >= 0 && kj < W)
            acc += S[idx + d * (W + 1)];
    }
    T[idx] = acc;
}

// ---------------------------------------------------------------------------
// 4) horizontal box sum: Vh[c,h,kk] = sum_{d} v[c,h,kk+d]
// ---------------------------------------------------------------------------
__global__ __launch_bounds__(256) void k_boxh(
    const float* __restrict__ v, float* __restrict__ Vh)
{
    const int idx = blockIdx.x * 256 + threadIdx.x;   // < C*NPIX
    const int kk = idx & 127;
    float acc = 0.f;
#pragma unroll
    for (int d = -PAD; d <= PAD; ++d) {
        int kj = kk + d;
        if (kj >= 0 && kj < W) acc += v[idx + d];
    }
    Vh[idx] = acc;
}

// ---------------------------------------------------------------------------
// 5) vertical box sum: Vs[c,h,kk] = sum_{d} Vh[c,h+d,kk]
// ---------------------------------------------------------------------------
__global__ __launch_bounds__(256) void k_boxv(
    const float* __restrict__ Vh, float* __restrict__ Vs)
{
    const int idx = blockIdx.x * 256 + threadIdx.x;   // < C*NPIX
    const int h = (idx >> 7) & 127;
    float acc = 0.f;
#pragma unroll
    for (int d = -PAD; d <= PAD; ++d) {
        int hj = h + d;
        if (hj >= 0 && hj < H) acc += Vh[idx + d * W];
    }
    Vs[idx] = acc;
}

// ---------------------------------------------------------------------------
// 6) vertical 7-sum of T + softmax over kk. grid (W, H), block 64 (one wave).
//    Each lane holds kk=lane and kk=lane+64.
// ---------------------------------------------------------------------------
__global__ __launch_bounds__(64) void k_softmax(
    const float* __restrict__ T, float* __restrict__ attn)
{
    const int w    = blockIdx.x;
    const int h    = blockIdx.y;
    const int lane = threadIdx.x;
    const int rowb = w * W;

    float L0 = 0.f, L1 = 0.f;
#pragma unroll
    for (int d = -PAD; d <= PAD; ++d) {
        int hj = h + d;
        if (hj >= 0 && hj < H) {
            const float* p = T + hj * NPIX + rowb;
            L0 += p[lane];
            L1 += p[lane + 64];
        }
    }
    float m = fmaxf(L0, L1);
#pragma unroll
    for (int off = 32; off > 0; off >>= 1) m = fmaxf(m, __shfl_xor(m, off));
    float e0 = __expf(L0 - m), e1 = __expf(L1 - m);
    float s = e0 + e1;
#pragma unroll
    for (int off = 32; off > 0; off >>= 1) s += __shfl_xor(s, off);
    float inv = 1.f / s;
    attn[h * NPIX + rowb + lane]      = e0 * inv;
    attn[h * NPIX + rowb + lane + 64] = e1 * inv;
}

// ---------------------------------------------------------------------------
// 7) out[c,h,w] = sum_kk attn[h,w,kk] * Vs[c,h,kk], write float.
//    grid (H, 2 c-halves), block 256. LDS: Vs half-row 16KB + attn chunk ~17KB.
// ---------------------------------------------------------------------------
__global__ __launch_bounds__(256) void k_out(
    const float* __restrict__ attn, const float* __restrict__ Vs,
    float* __restrict__ out)
{
    __shared__ float Vss[32][W];     // 32 channels x 128 k   (16 KB)
    __shared__ float As[W][33];      // 128 w x 32 k, padded  (~16.9 KB)
    const int h    = blockIdx.x;
    const int cblk = blockIdx.y * 32;
    const int tid  = threadIdx.x;

    for (int i = tid; i < 32 * W; i += 256) {
        int c = i >> 7, kk = i & 127;
        Vss[c][kk] = Vs[(cblk + c) * NPIX + h * W + kk];
    }

    const int w  = tid & 127;
    const int c0 = (tid >> 7) * 16;          // 0 or 16 within the 32-block
    float acc[16];
#pragma unroll
    for (int t = 0; t < 16; ++t) acc[t] = 0.f;

    for (int kc = 0; kc < W; kc += 32) {
        __syncthreads();                      // protects Vss (1st it) / As reuse
        for (int i = tid; i < W * 32; i += 256) {
            int ww = i >> 5, kk = i & 31;
            As[ww][kk] = attn[h * NPIX + ww * W + kc + kk];
        }
        __syncthreads();
        for (int kk = 0; kk < 32; ++kk) {
            float a = As[w][kk];
#pragma unroll
            for (int t = 0; t < 16; ++t) acc[t] += a * Vss[c0 + t][kc + kk];
        }
    }

#pragma unroll
    for (int t = 0; t < 16; ++t)
        out[(cblk + c0 + t) * NPIX + h * W + w] = acc[t];
}

// ---------------------------------------------------------------------------
// Workspace layout (floats), 5M floats = 20 MB total:
//   [0,1M)   q        -> reused as T[0..1M)     after k_gram
//   [1M,2M)  k        -> reused as T[1M..2M)    after k_gram
//   [2M,3M)  v        -> reused as attn[0..1M)  after k_boxh/boxv
//   [3M,5M)  S        -> [3M,4M) reused as Vh after k_diag, then attn[1M..2M)
//                        [4M,5M) reused as Vs
// Live sets at each stage verified: no producer overwrites a live consumer.
// ---------------------------------------------------------------------------
extern "C" void kernel_launch(void* const* d_in, const int* in_sizes, int n_in,
                              void* d_out, int out_size, void* d_ws, size_t ws_size,
                              hipStream_t stream)
{
    const float* x  = (const float*)d_in[0];
    const float* Wq = (const float*)d_in[1];
    const float* bq = (const float*)d_in[2];
    const float* Wk = (const float*)d_in[3];
    const float* bk = (const float*)d_in[4];
    const float* Wv = (const float*)d_in[5];
    const float* bv = (const float*)d_in[6];
    float* out = (float*)d_out;

    float* ws = (float*)d_ws;
    const size_t NQ = (size_t)C * NPIX;       // 1,048,576 floats (4 MB)
    const size_t NS = (size_t)H * W * W;      // 2,097,152 floats (8 MB)

    float* q    = ws;                 // [0, 1M)
    float* k    = ws + NQ;            // [1M, 2M)
    float* v    = ws + 2 * NQ;        // [2M, 3M)
    float* S    = ws + 3 * NQ;        // [3M, 5M)
    float* T    = ws;                 // [0, 2M)   over q+k (dead after gram)
    float* Vh   = ws + 3 * NQ;        // [3M, 4M)  over S-lo (S dead after diag)
    float* Vsum = ws + 4 * NQ;        // [4M, 5M)  over S-hi
    float* attn = ws + 2 * NQ;        // [2M, 4M)  over v+Vh (dead after boxv)

    k_conv<<<dim3(NPIX / 256, 3), 256, 0, stream>>>(x, Wq, bq, Wk, bk, Wv, bv, q, k, v);
    k_gram<<<dim3(H, 2), 256, 0, stream>>>(q, k, S);
    k_diag<<<dim3(NS / 256), 256, 0, stream>>>(S, T);
    k_boxh<<<dim3(NQ / 256), 256, 0, stream>>>(v, Vh);
    k_boxv<<<dim3(NQ / 256), 256, 0, stream>>>(Vh, Vsum);
    k_softmax<<<dim3(W, H), 64, 0, stream>>>(T, attn);
    k_out<<<dim3(H, 2), 256, 0, stream>>>(attn, Vsum, out);
}

// Round 4
// 172.740 us; speedup vs baseline: 1.1213x; 1.1213x over previous
//
#include <hip/hip_runtime.h>

static constexpr int C    = 64;
static constexpr int H    = 128;
static constexpr int W    = 128;
static constexpr int NPIX = H * W;      // 16384
static constexpr int PAD  = 3;          // WS=7 -> +-3

// ---------------------------------------------------------------------------
// 1) conv1x1. z=0: qT[pix][c] (transposed, float4 stores); z=1: k[c][pix];
//    z=2: v[c][pix]. W/b read directly from global with wave-uniform addresses
//    -> compiler emits scalar (SMEM) loads, inner loop is pure v_fmac v,s,v.
//    grid (NPIX/256, 3), block 256
// ---------------------------------------------------------------------------
__global__ __launch_bounds__(256) void k_conv(
    const float* __restrict__ x,
    const float* __restrict__ Wq, const float* __restrict__ bq,
    const float* __restrict__ Wk, const float* __restrict__ bk,
    const float* __restrict__ Wv, const float* __restrict__ bv,
    float* __restrict__ qT, float* __restrict__ ko, float* __restrict__ vo)
{
    const int tid = threadIdx.x;
    const int p   = blockIdx.x * 256 + tid;
    const int z   = blockIdx.y;
    const float* Wm = (z == 0) ? Wq : (z == 1) ? Wk : Wv;
    const float* bm = (z == 0) ? bq : (z == 1) ? bk : bv;

    float xr[C];
#pragma unroll
    for (int c = 0; c < C; ++c) xr[c] = x[c * NPIX + p];

    for (int o = 0; o < C; o += 4) {
        float a0 = bm[o], a1 = bm[o + 1], a2 = bm[o + 2], a3 = bm[o + 3];
#pragma unroll
        for (int c = 0; c < C; ++c) {
            a0 += Wm[(o + 0) * C + c] * xr[c];
            a1 += Wm[(o + 1) * C + c] * xr[c];
            a2 += Wm[(o + 2) * C + c] * xr[c];
            a3 += Wm[(o + 3) * C + c] * xr[c];
        }
        if (z == 0) {
            float4 st = make_float4(a0, a1, a2, a3);
            *(float4*)(qT + (size_t)p * C + o) = st;
        } else {
            float* outm = (z == 1) ? ko : vo;
            outm[(o + 0) * NPIX + p] = a0;
            outm[(o + 1) * NPIX + p] = a1;
            outm[(o + 2) * NPIX + p] = a2;
            outm[(o + 3) * NPIX + p] = a3;
        }
    }
}

// ---------------------------------------------------------------------------
// 2) row Gram: S[h, w, kk] = sum_c q[c,h,w] * k[c,h,kk]
//    k column register-cached (coalesced global); q row is wave-uniform ->
//    readfirstlane + qT row (pixel index h*W+w!) -> scalar loads feeding
//    v_fmac. Zero LDS. grid (H, 4 w-quarters), block 256
// ---------------------------------------------------------------------------
__global__ __launch_bounds__(256) void k_gram(
    const float* __restrict__ qT, const float* __restrict__ kmat,
    float* __restrict__ S)
{
    const int h   = blockIdx.x;
    const int q0  = blockIdx.y * 32;
    const int tid = threadIdx.x;
    const int kk  = tid & 127;
    const int wh  = tid >> 7;               // 0/1, uniform per wave

    float ksr[C];
#pragma unroll
    for (int c = 0; c < C; ++c) ksr[c] = kmat[c * NPIX + h * W + kk];

    for (int j = 0; j < 16; ++j) {
        int w  = q0 + wh * 16 + j;
        int wu = __builtin_amdgcn_readfirstlane(w);
        // pixel index = h*W + wu  (round-3 bug: used wu alone -> row-0 q)
        const float* qrow = qT + ((size_t)(h * W + wu)) * C;  // SGPR base
        float a0 = 0.f, a1 = 0.f, a2 = 0.f, a3 = 0.f;
#pragma unroll
        for (int c = 0; c < C; c += 4) {
            a0 += qrow[c + 0] * ksr[c + 0];
            a1 += qrow[c + 1] * ksr[c + 1];
            a2 += qrow[c + 2] * ksr[c + 2];
            a3 += qrow[c + 3] * ksr[c + 3];
        }
        S[(h * W + wu) * W + kk] = (a0 + a1) + (a2 + a3);
    }
}

// ---------------------------------------------------------------------------
// 3) diagonal 7-sum: T[h,w,kk] = sum_{d=-3..3} S[h, w+d, kk+d] (in-bounds)
// ---------------------------------------------------------------------------
__global__ __launch_bounds__(256) void k_diag(
    const float* __restrict__ S, float* __restrict__ T)
{
    const int idx = blockIdx.x * 256 + threadIdx.x;   // < H*W*W
    const int kk = idx & 127;
    const int w  = (idx >> 7) & 127;
    float acc = 0.f;
#pragma unroll
    for (int d = -PAD; d <= PAD; ++d) {
        int wj = w + d, kj = kk + d;
        if (wj >= 0 && wj < W && kj >= 0 && kj < W)
            acc += S[idx + d * (W + 1)];
    }
    T[idx] = acc;
}

// ---------------------------------------------------------------------------
// 4) fused 7x7 box sum of v: Vs[c,h,w] = sum_{dh,dw} v[c,h+dh,w+dw]
//    LDS-tiled separable (horizontal then vertical), one kernel.
//    grid (C, H/16), block 256
// ---------------------------------------------------------------------------
__global__ __launch_bounds__(256) void k_box(
    const float* __restrict__ v, float* __restrict__ Vs)
{
    __shared__ float vt[22][128];    // rows h0-3 .. h0+18, zero-padded
    __shared__ float vh[22][128];    // horizontal 7-sums
    const int c   = blockIdx.x;
    const int h0  = blockIdx.y * 16;
    const int tid = threadIdx.x;

    for (int i = tid; i < 22 * 128; i += 256) {
        int r = i >> 7, w = i & 127;
        int h = h0 - 3 + r;
        vt[r][w] = (h >= 0 && h < H) ? v[c * NPIX + h * W + w] : 0.f;
    }
    __syncthreads();
    for (int i = tid; i < 22 * 128; i += 256) {
        int r = i >> 7, w = i & 127;
        float s = 0.f;
#pragma unroll
        for (int d = -PAD; d <= PAD; ++d) {
            int wj = w + d;
            if (wj >= 0 && wj < W) s += vt[r][wj];
        }
        vh[r][w] = s;
    }
    __syncthreads();
    for (int i = tid; i < 16 * 128; i += 256) {
        int r = i >> 7, w = i & 127;
        float s = 0.f;
#pragma unroll
        for (int d = 0; d < 7; ++d) s += vh[r + d][w];
        Vs[c * NPIX + (h0 + r) * W + w] = s;
    }
}

// ---------------------------------------------------------------------------
// 5) vertical 7-sum of T + softmax over kk. grid (W, H), block 64 (one wave).
// ---------------------------------------------------------------------------
__global__ __launch_bounds__(64) void k_softmax(
    const float* __restrict__ T, float* __restrict__ attn)
{
    const int w    = blockIdx.x;
    const int h    = blockIdx.y;
    const int lane = threadIdx.x;
    const int rowb = w * W;

    float L0 = 0.f, L1 = 0.f;
#pragma unroll
    for (int d = -PAD; d <= PAD; ++d) {
        int hj = h + d;
        if (hj >= 0 && hj < H) {
            const float* p = T + hj * NPIX + rowb;
            L0 += p[lane];
            L1 += p[lane + 64];
        }
    }
    float m = fmaxf(L0, L1);
#pragma unroll
    for (int off = 32; off > 0; off >>= 1) m = fmaxf(m, __shfl_xor(m, off));
    float e0 = __expf(L0 - m), e1 = __expf(L1 - m);
    float s = e0 + e1;
#pragma unroll
    for (int off = 32; off > 0; off >>= 1) s += __shfl_xor(s, off);
    float inv = 1.f / s;
    attn[h * NPIX + rowb + lane]      = e0 * inv;
    attn[h * NPIX + rowb + lane + 64] = e1 * inv;
}

// ---------------------------------------------------------------------------
// 6) out[c,h,w] = sum_kk attn[h,w,kk] * Vs[c,h,kk]
//    Vs transposed into LDS [kk][c] (pad 36 -> 16B-aligned b128 broadcasts);
//    attn chunked [w][kk] read as float4. grid (H, 2 c-halves), block 256.
// ---------------------------------------------------------------------------
__global__ __launch_bounds__(256) void k_out(
    const float* __restrict__ attn, const float* __restrict__ Vs,
    float* __restrict__ out)
{
    __shared__ float Vst[W][36];     // [kk][c-local], 18 KB
    __shared__ float As[W][36];      // [w][kk-chunk of 32], 18 KB
    const int h    = blockIdx.x;
    const int cblk = blockIdx.y * 32;
    const int tid  = threadIdx.x;

    for (int i = tid; i < 32 * W; i += 256) {
        int c = i >> 7, kk = i & 127;
        Vst[kk][c] = Vs[(cblk + c) * NPIX + h * W + kk];
    }

    const int w  = tid & 127;
    const int c0 = (tid >> 7) * 16;          // 0 or 16 within the 32-block
    float acc[16];
#pragma unroll
    for (int t = 0; t < 16; ++t) acc[t] = 0.f;

    for (int kc = 0; kc < W; kc += 32) {
        __syncthreads();                      // guards Vst (1st it) / As reuse
        for (int i = tid; i < W * 32; i += 256) {
            int ww = i >> 5, kk = i & 31;
            As[ww][kk] = attn[h * NPIX + ww * W + kc + kk];
        }
        __syncthreads();
        for (int kk = 0; kk < 32; kk += 4) {
            float4 av = *(const float4*)&As[w][kk];
            const float af[4] = {av.x, av.y, av.z, av.w};
#pragma unroll
            for (int u = 0; u < 4; ++u) {
                float a = af[u];
                int kg = kc + kk + u;
                float4 b0 = *(const float4*)&Vst[kg][c0 + 0];
                float4 b1 = *(const float4*)&Vst[kg][c0 + 4];
                float4 b2 = *(const float4*)&Vst[kg][c0 + 8];
                float4 b3 = *(const float4*)&Vst[kg][c0 + 12];
                acc[0]  += a * b0.x; acc[1]  += a * b0.y;
                acc[2]  += a * b0.z; acc[3]  += a * b0.w;
                acc[4]  += a * b1.x; acc[5]  += a * b1.y;
                acc[6]  += a * b1.z; acc[7]  += a * b1.w;
                acc[8]  += a * b2.x; acc[9]  += a * b2.y;
                acc[10] += a * b2.z; acc[11] += a * b2.w;
                acc[12] += a * b3.x; acc[13] += a * b3.y;
                acc[14] += a * b3.z; acc[15] += a * b3.w;
            }
        }
    }

#pragma unroll
    for (int t = 0; t < 16; ++t)
        out[(cblk + c0 + t) * NPIX + h * W + w] = acc[t];
}

// ---------------------------------------------------------------------------
// Workspace: 10M floats = 40 MB, non-overlapping (ws is 268 MB).
//   qT [0,1M)  k [1M,2M)  v [2M,3M)  S [3M,5M)  T [5M,7M)  Vs [7M,8M)
//   attn [8M,10M)
// ---------------------------------------------------------------------------
extern "C" void kernel_launch(void* const* d_in, const int* in_sizes, int n_in,
                              void* d_out, int out_size, void* d_ws, size_t ws_size,
                              hipStream_t stream)
{
    const float* x  = (const float*)d_in[0];
    const float* Wq = (const float*)d_in[1];
    const float* bq = (const float*)d_in[2];
    const float* Wk = (const float*)d_in[3];
    const float* bk = (const float*)d_in[4];
    const float* Wv = (const float*)d_in[5];
    const float* bv = (const float*)d_in[6];
    float* out = (float*)d_out;

    float* ws = (float*)d_ws;
    const size_t NQ = (size_t)C * NPIX;       // 1M floats
    const size_t NS = (size_t)H * W * W;      // 2M floats

    float* qT   = ws;
    float* k    = ws + NQ;
    float* v    = ws + 2 * NQ;
    float* S    = ws + 3 * NQ;
    float* T    = ws + 3 * NQ + NS;
    float* Vsum = ws + 3 * NQ + 2 * NS;
    float* attn = ws + 4 * NQ + 2 * NS;

    k_conv<<<dim3(NPIX / 256, 3), 256, 0, stream>>>(x, Wq, bq, Wk, bk, Wv, bv, qT, k, v);
    k_gram<<<dim3(H, 4), 256, 0, stream>>>(qT, k, S);
    k_diag<<<dim3(NS / 256), 256, 0, stream>>>(S, T);
    k_box<<<dim3(C, H / 16), 256, 0, stream>>>(v, Vsum);
    k_softmax<<<dim3(W, H), 64, 0, stream>>>(T, attn);
    k_out<<<dim3(H, 2), 256, 0, stream>>>(attn, Vsum, out);
}

// Round 5
// 157.946 us; speedup vs baseline: 1.2263x; 1.0937x over previous
//
#include <hip/hip_runtime.h>

static constexpr int C    = 64;
static constexpr int H    = 128;
static constexpr int W    = 128;
static constexpr int NPIX = H * W;      // 16384
static constexpr int PAD  = 3;          // WS=7 -> +-3

// ---------------------------------------------------------------------------
// 1) conv1x1. Each wave handles 64 pixels x 16 output channels; W/b rows are
//    wave-uniform -> scalar (SMEM) loads feeding v_fmac v,s,v. 16 independent
//    acc chains for ILP. z=0 writes qT[pix][c] (float4), z=1/2 write [c][pix].
//    grid (NPIX/64, 3) = 768 blocks, block 256 (4 waves = 4 o-chunks)
// ---------------------------------------------------------------------------
__global__ __launch_bounds__(256) void k_conv(
    const float* __restrict__ x,
    const float* __restrict__ Wq, const float* __restrict__ bq,
    const float* __restrict__ Wk, const float* __restrict__ bk,
    const float* __restrict__ Wv, const float* __restrict__ bv,
    float* __restrict__ qT, float* __restrict__ ko, float* __restrict__ vo)
{
    const int tid  = threadIdx.x;
    const int lane = tid & 63;
    const int p    = blockIdx.x * 64 + lane;
    const int o0   = __builtin_amdgcn_readfirstlane((tid >> 6) * 16);
    const int z    = blockIdx.y;
    const float* Wm = (z == 0) ? Wq : (z == 1) ? Wk : Wv;
    const float* bm = (z == 0) ? bq : (z == 1) ? bk : bv;

    float xr[C];
#pragma unroll
    for (int c = 0; c < C; ++c) xr[c] = x[c * NPIX + p];

    float acc[16];
#pragma unroll
    for (int j = 0; j < 16; ++j) acc[j] = bm[o0 + j];

#pragma unroll 8
    for (int c = 0; c < C; ++c) {
        const float xv = xr[c];
#pragma unroll
        for (int j = 0; j < 16; ++j)
            acc[j] += Wm[(o0 + j) * C + c] * xv;
    }

    if (z == 0) {
#pragma unroll
        for (int j = 0; j < 16; j += 4)
            *(float4*)(qT + (size_t)p * C + o0 + j) =
                make_float4(acc[j], acc[j + 1], acc[j + 2], acc[j + 3]);
    } else {
        float* outm = (z == 1) ? ko : vo;
#pragma unroll
        for (int j = 0; j < 16; ++j)
            outm[(o0 + j) * NPIX + p] = acc[j];
    }
}

// ---------------------------------------------------------------------------
// 2) row Gram: S[h, w, kk] = sum_c q[c,h,w] * k[c,h,kk]
//    k column register-cached (coalesced); q row wave-uniform -> s_load.
//    grid (H, 8) = 1024 blocks (16 w each), block 256
// ---------------------------------------------------------------------------
__global__ __launch_bounds__(256) void k_gram(
    const float* __restrict__ qT, const float* __restrict__ kmat,
    float* __restrict__ S)
{
    const int h   = blockIdx.x;
    const int w0  = blockIdx.y * 16;
    const int tid = threadIdx.x;
    const int kk  = tid & 127;
    const int wh  = tid >> 7;               // 0/1, uniform per wave

    float ksr[C];
#pragma unroll
    for (int c = 0; c < C; ++c) ksr[c] = kmat[c * NPIX + h * W + kk];

    for (int j = 0; j < 8; ++j) {
        int wu = __builtin_amdgcn_readfirstlane(w0 + wh * 8 + j);
        const float* qrow = qT + (size_t)(h * W + wu) * C;  // SGPR base
        float a0 = 0.f, a1 = 0.f, a2 = 0.f, a3 = 0.f;
#pragma unroll
        for (int c = 0; c < C; c += 4) {
            a0 += qrow[c + 0] * ksr[c + 0];
            a1 += qrow[c + 1] * ksr[c + 1];
            a2 += qrow[c + 2] * ksr[c + 2];
            a3 += qrow[c + 3] * ksr[c + 3];
        }
        S[(h * W + wu) * W + kk] = (a0 + a1) + (a2 + a3);
    }
}

// ---------------------------------------------------------------------------
// 3) diagonal 7-sum: T[h,w,kk] = sum_{d=-3..3} S[h, w+d, kk+d] (in-bounds)
// ---------------------------------------------------------------------------
__global__ __launch_bounds__(256) void k_diag(
    const float* __restrict__ S, float* __restrict__ T)
{
    const int idx = blockIdx.x * 256 + threadIdx.x;   // < H*W*W
    const int kk = idx & 127;
    const int w  = (idx >> 7) & 127;
    float acc = 0.f;
#pragma unroll
    for (int d = -PAD; d <= PAD; ++d) {
        int wj = w + d, kj = kk + d;
        if (wj >= 0 && wj < W && kj >= 0 && kj < W)
            acc += S[idx + d * (W + 1)];
    }
    T[idx] = acc;
}

// ---------------------------------------------------------------------------
// 4) fused 7x7 box sum of v. grid (C, H/16), block 256
// ---------------------------------------------------------------------------
__global__ __launch_bounds__(256) void k_box(
    const float* __restrict__ v, float* __restrict__ Vs)
{
    __shared__ float vt[22][128];    // rows h0-3 .. h0+18, zero-padded
    __shared__ float vh[22][128];    // horizontal 7-sums
    const int c   = blockIdx.x;
    const int h0  = blockIdx.y * 16;
    const int tid = threadIdx.x;

    for (int i = tid; i < 22 * 128; i += 256) {
        int r = i >> 7, w = i & 127;
        int h = h0 - 3 + r;
        vt[r][w] = (h >= 0 && h < H) ? v[c * NPIX + h * W + w] : 0.f;
    }
    __syncthreads();
    for (int i = tid; i < 22 * 128; i += 256) {
        int r = i >> 7, w = i & 127;
        float s = 0.f;
#pragma unroll
        for (int d = -PAD; d <= PAD; ++d) {
            int wj = w + d;
            if (wj >= 0 && wj < W) s += vt[r][wj];
        }
        vh[r][w] = s;
    }
    __syncthreads();
    for (int i = tid; i < 16 * 128; i += 256) {
        int r = i >> 7, w = i & 127;
        float s = 0.f;
#pragma unroll
        for (int d = 0; d < 7; ++d) s += vh[r + d][w];
        Vs[c * NPIX + (h0 + r) * W + w] = s;
    }
}

// ---------------------------------------------------------------------------
// 5) vertical 7-sum of T + softmax over kk. grid (W, H), block 64 (one wave).
// ---------------------------------------------------------------------------
__global__ __launch_bounds__(64) void k_softmax(
    const float* __restrict__ T, float* __restrict__ attn)
{
    const int w    = blockIdx.x;
    const int h    = blockIdx.y;
    const int lane = threadIdx.x;
    const int rowb = w * W;

    float L0 = 0.f, L1 = 0.f;
#pragma unroll
    for (int d = -PAD; d <= PAD; ++d) {
        int hj = h + d;
        if (hj >= 0 && hj < H) {
            const float* p = T + hj * NPIX + rowb;
            L0 += p[lane];
            L1 += p[lane + 64];
        }
    }
    float m = fmaxf(L0, L1);
#pragma unroll
    for (int off = 32; off > 0; off >>= 1) m = fmaxf(m, __shfl_xor(m, off));
    float e0 = __expf(L0 - m), e1 = __expf(L1 - m);
    float s = e0 + e1;
#pragma unroll
    for (int off = 32; off > 0; off >>= 1) s += __shfl_xor(s, off);
    float inv = 1.f / s;
    attn[h * NPIX + rowb + lane]      = e0 * inv;
    attn[h * NPIX + rowb + lane + 64] = e1 * inv;
}

// ---------------------------------------------------------------------------
// 6) out[c,h,w] = sum_kk attn[h,w,kk] * Vs[c,h,kk]  — gram-style:
//    lanes = w, channels wave-uniform -> Vs via s_load (scalar cache),
//    attn staged in LDS (padded, conflict-free), 8 acc chains.
//    grid (H, C/16) = 512 blocks, block 256 (2 c-groups of 8 per block)
// ---------------------------------------------------------------------------
__global__ __launch_bounds__(256) void k_out(
    const float* __restrict__ attn, const float* __restrict__ Vs,
    float* __restrict__ out)
{
    __shared__ float As[W][65];      // [w][kk-chunk of 64], 33.3 KB
    const int h   = blockIdx.x;
    const int tid = threadIdx.x;
    const int w   = tid & 127;
    const int c0  = __builtin_amdgcn_readfirstlane(
                        blockIdx.y * 16 + (tid >> 7) * 8);
    const int hb  = h * W;

    float acc[8];
#pragma unroll
    for (int j = 0; j < 8; ++j) acc[j] = 0.f;

    for (int kc = 0; kc < W; kc += 64) {
        __syncthreads();
        for (int i = tid; i < W * 64; i += 256) {
            int kk = i & 63, ww = i >> 6;
            As[ww][kk] = attn[(size_t)h * NPIX + ww * W + kc + kk];
        }
        __syncthreads();
#pragma unroll 4
        for (int kk = 0; kk < 64; ++kk) {
            float a = As[w][kk];
#pragma unroll
            for (int j = 0; j < 8; ++j)
                acc[j] += Vs[(size_t)(c0 + j) * NPIX + hb + kc + kk] * a;
        }
    }

#pragma unroll
    for (int j = 0; j < 8; ++j)
        out[(size_t)(c0 + j) * NPIX + hb + w] = acc[j];
}

// ---------------------------------------------------------------------------
// Workspace: 10M floats = 40 MB, non-overlapping (ws is 268 MB).
//   qT [0,1M)  k [1M,2M)  v [2M,3M)  S [3M,5M)  T [5M,7M)  Vs [7M,8M)
//   attn [8M,10M)
// ---------------------------------------------------------------------------
extern "C" void kernel_launch(void* const* d_in, const int* in_sizes, int n_in,
                              void* d_out, int out_size, void* d_ws, size_t ws_size,
                              hipStream_t stream)
{
    const float* x  = (const float*)d_in[0];
    const float* Wq = (const float*)d_in[1];
    const float* bq = (const float*)d_in[2];
    const float* Wk = (const float*)d_in[3];
    const float* bk = (const float*)d_in[4];
    const float* Wv = (const float*)d_in[5];
    const float* bv = (const float*)d_in[6];
    float* out = (float*)d_out;

    float* ws = (float*)d_ws;
    const size_t NQ = (size_t)C * NPIX;       // 1M floats
    const size_t NS = (size_t)H * W * W;      // 2M floats

    float* qT   = ws;
    float* k    = ws + NQ;
    float* v    = ws + 2 * NQ;
    float* S    = ws + 3 * NQ;
    float* T    = ws + 3 * NQ + NS;
    float* Vsum = ws + 3 * NQ + 2 * NS;
    float* attn = ws + 4 * NQ + 2 * NS;

    k_conv<<<dim3(NPIX / 64, 3), 256, 0, stream>>>(x, Wq, bq, Wk, bk, Wv, bv, qT, k, v);
    k_gram<<<dim3(H, 8), 256, 0, stream>>>(qT, k, S);
    k_diag<<<dim3(NS / 256), 256, 0, stream>>>(S, T);
    k_box<<<dim3(C, H / 16), 256, 0, stream>>>(v, Vsum);
    k_softmax<<<dim3(W, H), 64, 0, stream>>>(T, attn);
    k_out<<<dim3(H, 4), 256, 0, stream>>>(attn, Vsum, out);
}